// Round 9
// baseline (78.555 us; speedup 1.0000x reference)
//
#include <hip/hip_runtime.h>

#define LN2 0.6931471805599453f

// lane i <- lane i-1 (value), lane 0 <- 0.0f   (wave_shr:1)
__device__ __forceinline__ float dpp_shr1_zero(float x) {
    return __int_as_float(__builtin_amdgcn_update_dpp(
        0, __float_as_int(x), 0x138, 0xF, 0xF, true));
}
// lane i <- lane i-1 (int), lane 0 keeps own
__device__ __forceinline__ int dpp_shr1_keep(int x) {
    return __builtin_amdgcn_update_dpp(x, x, 0x138, 0xF, 0xF, false);
}
// exact 2^clamp(d, -126, 127)
__device__ __forceinline__ float exp2i_clamped(int d) {
    int k = 127 + d;
    k = (k < 1) ? 1 : ((k > 254) ? 254 : k);
    return __uint_as_float(((unsigned)k) << 23);
}
// broadcast lane ln's value to all lanes (v_readlane -> SGPR, no memory)
__device__ __forceinline__ float rlf(float v, int ln) {
    return __int_as_float(__builtin_amdgcn_readlane(__float_as_int(v), ln));
}

struct FwdState {
    float a0, a1, a2;   // lane's 3 lattice states (linear, scaled by 2^-esum)
    float s1, k0, k1;   // 2^(eL-e), skm0*s1, skm1*s1
    int   esum;
};

// 11 VALU per step (proven exact in R4-R6)
__device__ __forceinline__ void fwd_step(float em0, float em1, float em2,
                                         FwdState& st, float skm2) {
    float d2 = dpp_shr1_zero(st.a2);    // alpha[l0-1] (left-neighbor scale)
    float d1 = dpp_shr1_zero(st.a1);    // alpha[l0-2]
    float n0 = fmaf(st.k0, d1, fmaf(st.s1, d2, st.a0)) * em0;
    float n1 = fmaf(st.k1, d2, st.a1 + st.a0) * em1;
    float n2 = fmaf(skm2, st.a0, st.a2 + st.a1) * em2;
    st.a0 = n0; st.a1 = n1; st.a2 = n2;
}

// Every 8 steps: per-lane pow2 renorm + dead-lane exponent adoption (5-deep)
// + gap clamp (<= 2^64). All exact (exponent-only). Proven in R6.
__device__ __forceinline__ void fwd_rescale(FwdState& st, float skm0, float skm1) {
    float m = fmaxf(fmaxf(st.a0, st.a1), st.a2);
    int ebits = (int)(__float_as_uint(m) >> 23);
    bool dead = (ebits == 0);
    int de = dead ? 0 : (127 - ebits);
    float scz = dead ? 0.0f : exp2i_clamped(de);
    st.a0 *= scz; st.a1 *= scz; st.a2 *= scz;
    st.esum -= de;
    #pragma unroll
    for (int r = 0; r < 5; ++r) {
        int en = dpp_shr1_keep(st.esum);
        st.esum = dead ? en : st.esum;
    }
    int enf = dpp_shr1_keep(st.esum);
    int gap = enf - st.esum;
    int adj = (gap > 64) ? (gap - 64) : 0;
    float sc3 = exp2i_clamped(-adj);
    st.a0 *= sc3; st.a1 *= sc3; st.a2 *= sc3;
    st.esum += adj;
    st.s1 = exp2i_clamped(gap - adj);
    st.k0 = skm0 * st.s1;
    st.k1 = skm1 * st.s1;
}

// One wave per (b,f). Lane owns 3 adjacent lattice states (linear domain,
// per-lane block-floating-point). Emissions are REGISTER-RESIDENT, distributed
// across lanes (lane k holds rows t==k mod 64: {delta=p1-p0, dpb=p0-pb, pb}).
// Per step: 3x v_readlane broadcast + 5 fma reconstruct. No memory in hot loop.
__global__ __launch_bounds__(64, 1) void ctc_kernel(
    const float* __restrict__ logits,        // [T, B, 2F+1]
    const int* __restrict__ targets,         // [B, F, S]
    const int* __restrict__ input_lengths,   // [B]
    const int* __restrict__ target_lengths,  // [B, F]
    float* __restrict__ loss_out,            // [B*F] (loss / tl)
    int T, int B, int Ff, int S)
{
    const int p = blockIdx.x;
    const int b = p / Ff;
    const int f = p - b * Ff;
    const int lane = (int)threadIdx.x;
    const int C = 2 * Ff + 1;
    const int L = 2 * S + 1;

    const int tl = target_lengths[p];
    const int il = input_lengths[b];
    const int tbase = p * S;

    // ---- per-lane static metadata: states l = 3*lane + j ----
    // tf_j: target bit (float) for odd in-range states, else 0.
    // skm_j: skip-transition mask. vP/vQ: parity of states {0,2} / {1}.
    float tf0, tf1, tf2, skm0, skm1, skm2;
    {
        float tf[3], sk[3];
        const int l0 = 3 * lane;
        #pragma unroll
        for (int j = 0; j < 3; ++j) {
            int l = l0 + j;
            float tv = 0.f, sok = 0.f;
            if (l < L && (l & 1)) {
                int s = (l - 1) >> 1;
                int ev = targets[tbase + s];
                tv = (float)ev;
                if (s >= 1) sok = (targets[tbase + s - 1] != ev) ? 1.f : 0.f;
            }
            tf[j] = tv; sk[j] = sok;
        }
        tf0 = tf[0]; tf1 = tf[1]; tf2 = tf[2];
        skm0 = sk[0]; skm1 = sk[1]; skm2 = sk[2];
    }
    const float vP = (float)(lane & 1);   // odd_0 = odd_2
    const float vQ = 1.0f - vP;           // odd_1

    // ---- stage all 600 rows into registers (10 windows x 64 lanes) ----
    float qd[10], qdp[10], qpb[10];
    {
        const float* lg = logits + (size_t)b * C;
        const size_t strideT = (size_t)B * C;
        float r0[10], r1[10], r2[10];
        #pragma unroll
        for (int w = 0; w < 10; ++w) {     // issue all 30 loads (clamped addr)
            int i = (w << 6) + lane;
            int ic = (i < T) ? i : 0;
            const float* r = lg + (size_t)ic * strideT;
            r0[w] = r[f]; r1[w] = r[Ff + f]; r2[w] = r[2 * Ff];
        }
        #pragma unroll
        for (int w = 0; w < 10; ++w) {     // softmax per row
            float m = fmaxf(fmaxf(r0[w], r1[w]), r2[w]);
            float ep = __expf(r0[w] - m);
            float en = __expf(r1[w] - m);
            float eb = __expf(r2[w] - m);
            float inv = __builtin_amdgcn_rcpf(ep + en + eb);
            float p0 = ep * inv, p1 = en * inv, pb = eb * inv;
            bool valid = ((w << 6) + lane) < T;
            qd[w]  = valid ? (p1 - p0) : 0.f;
            qdp[w] = valid ? (p0 - pb) : 0.f;
            qpb[w] = valid ? pb : 0.f;
        }
    }

    // ---- t = 0 init ----
    FwdState fs;
    {
        float sd  = rlf(qd[0], 0);
        float sdp = rlf(qdp[0], 0);
        float spb = rlf(qpb[0], 0);
        float p00 = sdp + spb;                       // p_pos of row 0
        fs.a0 = (lane == 0) ? spb : 0.f;             // state 0 = blank
        fs.a1 = (lane == 0 && tl > 0) ? fmaf(tf1, sd, p00) : 0.f;
        fs.a2 = 0.f;
        fs.s1 = 1.f; fs.k0 = skm0; fs.k1 = skm1;
        fs.esum = 0;
    }

    const int t_end = (il < T) ? il : T;
    int t = 1;

#define STEP1(w) { \
    int ln = t & 63; \
    float sd  = rlf(qd[w], ln); \
    float sdp = rlf(qdp[w], ln); \
    float spb = rlf(qpb[w], ln); \
    float iA = fmaf(vP, sdp, spb); \
    float iB = fmaf(vQ, sdp, spb); \
    float e0 = fmaf(tf0, sd, iA); \
    float e1 = fmaf(tf1, sd, iB); \
    float e2 = fmaf(tf2, sd, iA); \
    fwd_step(e0, e1, e2, fs, skm2); \
    ++t; }

#define WINDOW(w) if (t < t_end) { \
    int tB = ((w) + 1) << 6; tB = (tB < t_end) ? tB : t_end; \
    while (t < tB && (t & 7)) STEP1(w)                       \
    while (t + 8 <= tB) { fwd_rescale(fs, skm0, skm1);       \
        STEP1(w) STEP1(w) STEP1(w) STEP1(w)                  \
        STEP1(w) STEP1(w) STEP1(w) STEP1(w) }                \
    while (t < tB) STEP1(w)                                  \
}

    WINDOW(0) WINDOW(1) WINDOW(2) WINDOW(3) WINDOW(4)
    WINDOW(5) WINDOW(6) WINDOW(7) WINDOW(8) WINDOW(9)

#undef STEP1
#undef WINDOW

    // ---- epilogue: loss from alpha[2tl], alpha[2tl-1] with per-lane exponents ----
    __shared__ float sa[192];
    __shared__ int   se[64];
    {
        int l = 3 * lane;
        sa[l] = fs.a0; sa[l + 1] = fs.a1; sa[l + 2] = fs.a2;
        se[lane] = fs.esum;
    }
    __syncthreads();
    if (lane == 0) {
        int l1 = 2 * tl;
        int l2 = (tl > 0) ? (2 * tl - 1) : 0;
        float v1 = sa[l1];
        float v2 = (tl > 0) ? sa[l2] : 0.f;
        int e1 = se[l1 / 3];
        int e2 = (tl > 0) ? se[l2 / 3] : 0;
        int em_ = (e1 > e2) ? e1 : e2;
        float sum = ldexpf(v1, e1 - em_) + ldexpf(v2, e2 - em_);
        float ll = (__log2f(sum) + (float)em_) * LN2;
        float loss = (ll > -1e29f) ? -ll : 0.0f;
        float denom = (tl > 0) ? (float)tl : 1.0f;
        loss_out[p] = loss / denom;
    }
}

// Deterministic single-block reduction: out[0] = sum(v) / B
__global__ __launch_bounds__(256) void reduce_kernel(
    const float* __restrict__ v, float* __restrict__ out, int n, float invB)
{
    __shared__ float buf[256];
    float s = 0.f;
    for (int i = (int)threadIdx.x; i < n; i += 256) s += v[i];
    buf[threadIdx.x] = s;
    __syncthreads();
    for (int off = 128; off > 0; off >>= 1) {
        if ((int)threadIdx.x < off) buf[threadIdx.x] += buf[threadIdx.x + off];
        __syncthreads();
    }
    if (threadIdx.x == 0) out[0] = buf[0] * invB;
}

extern "C" void kernel_launch(void* const* d_in, const int* in_sizes, int n_in,
                              void* d_out, int out_size, void* d_ws, size_t ws_size,
                              hipStream_t stream) {
    const float* logits         = (const float*)d_in[0];
    const int*   targets        = (const int*)d_in[1];
    const int*   input_lengths  = (const int*)d_in[2];
    const int*   target_lengths = (const int*)d_in[3];
    float* out = (float*)d_out;

    const int B  = in_sizes[2];            // 32
    const int BF = in_sizes[3];            // B*F = 1120
    const int Ff = BF / B;                 // 35
    const int S  = in_sizes[1] / BF;       // 80
    const int C  = 2 * Ff + 1;             // 71
    const int T  = in_sizes[0] / (B * C);  // 600

    float* losses = (float*)d_ws;          // BF floats of scratch

    ctc_kernel<<<BF, 64, 0, stream>>>(logits, targets, input_lengths,
                                      target_lengths, losses, T, B, Ff, S);
    reduce_kernel<<<1, 256, 0, stream>>>(losses, out, BF, 1.0f / (float)B);
}

// Round 11
// 63.374 us; speedup vs baseline: 1.2396x; 1.2396x over previous
//
#include <hip/hip_runtime.h>

#define LN2 0.6931471805599453f

typedef float f32x4 __attribute__((ext_vector_type(4)));

// lane i <- lane i-1 (value), lane 0 <- 0.0f   (wave_shr:1)
__device__ __forceinline__ float dpp_shr1_zero(float x) {
    return __int_as_float(__builtin_amdgcn_update_dpp(
        0, __float_as_int(x), 0x138, 0xF, 0xF, true));
}
// lane i <- lane i-1 (int), lane 0 keeps own
__device__ __forceinline__ int dpp_shr1_keep(int x) {
    return __builtin_amdgcn_update_dpp(x, x, 0x138, 0xF, 0xF, false);
}
// exact 2^clamp(d, -126, 127)
__device__ __forceinline__ float exp2i_clamped(int d) {
    int k = 127 + d;
    k = (k < 1) ? 1 : ((k > 254) ? 254 : k);
    return __uint_as_float(((unsigned)k) << 23);
}

struct FwdState {
    float a0, a1, a2;   // lane's 3 lattice states (linear, scaled by 2^-esum)
    float s1, k0, k1;   // 2^(eL-e), skm0*s1, skm1*s1
    int   esum;
};

// 11 VALU per step (proven exact R4-R9)
__device__ __forceinline__ void fwd_step(float em0, float em1, float em2,
                                         FwdState& st, float skm2) {
    float d2 = dpp_shr1_zero(st.a2);    // alpha[l0-1] (left-neighbor scale)
    float d1 = dpp_shr1_zero(st.a1);    // alpha[l0-2]
    float n0 = fmaf(st.k0, d1, fmaf(st.s1, d2, st.a0)) * em0;
    float n1 = fmaf(st.k1, d2, st.a1 + st.a0) * em1;
    float n2 = fmaf(skm2, st.a0, st.a2 + st.a1) * em2;
    st.a0 = n0; st.a1 = n1; st.a2 = n2;
}

// Every 8 steps: per-lane pow2 renorm + dead-lane exponent adoption (5-deep)
// + gap clamp (<= 2^64). All exact (exponent-only). Proven R6/R9.
__device__ __forceinline__ void fwd_rescale(FwdState& st, float skm0, float skm1) {
    float m = fmaxf(fmaxf(st.a0, st.a1), st.a2);
    int ebits = (int)(__float_as_uint(m) >> 23);
    bool dead = (ebits == 0);
    int de = dead ? 0 : (127 - ebits);
    float scz = dead ? 0.0f : exp2i_clamped(de);
    st.a0 *= scz; st.a1 *= scz; st.a2 *= scz;
    st.esum -= de;
    #pragma unroll
    for (int r = 0; r < 5; ++r) {
        int en = dpp_shr1_keep(st.esum);
        st.esum = dead ? en : st.esum;
    }
    int enf = dpp_shr1_keep(st.esum);
    int gap = enf - st.esum;
    int adj = (gap > 64) ? (gap - 64) : 0;
    float sc3 = exp2i_clamped(-adj);
    st.a0 *= sc3; st.a1 *= sc3; st.a2 *= sc3;
    st.esum += adj;
    st.s1 = exp2i_clamped(gap - adj);
    st.k0 = skm0 * st.s1;
    st.k1 = skm1 * st.s1;
}

// One wave per (b,f). Lane owns 3 adjacent lattice states (linear domain,
// per-lane block-floating-point). Rows in LDS as {d=p1-p0, p0-pb, pb, 0}.
// Hot loop: double-banked batches of 8 plain C++ ds_read_b128 into named
// registers, fenced by an empty asm "+v" ANCHOR — forces batched issue + ONE
// compiler-emitted (correct-by-construction) wait per bank, with the other
// bank's loads in flight underneath the 8 compute steps.
__global__ __launch_bounds__(64, 1) void ctc_kernel(
    const float* __restrict__ logits,        // [T, B, 2F+1]
    const int* __restrict__ targets,         // [B, F, S]
    const int* __restrict__ input_lengths,   // [B]
    const int* __restrict__ target_lengths,  // [B, F]
    float* __restrict__ loss_out,            // [B*F] (loss / tl)
    int T, int B, int Ff, int S)
{
    const int p = blockIdx.x;
    const int b = p / Ff;
    const int f = p - b * Ff;
    const int lane = (int)threadIdx.x;
    const int C = 2 * Ff + 1;
    const int L = 2 * S + 1;

    const int tl = target_lengths[p];
    const int il = input_lengths[b];
    const int tbase = p * S;

    // ---- per-lane static metadata: states l = 3*lane + j ----
    float tf0, tf1, tf2, skm0, skm1, skm2;
    {
        float tf[3], sk[3];
        const int l0 = 3 * lane;
        #pragma unroll
        for (int j = 0; j < 3; ++j) {
            int l = l0 + j;
            float tv = 0.f, sok = 0.f;
            if (l < L && (l & 1)) {
                int s = (l - 1) >> 1;
                int ev = targets[tbase + s];
                tv = (float)ev;
                if (s >= 1) sok = (targets[tbase + s - 1] != ev) ? 1.f : 0.f;
            }
            tf[j] = tv; sk[j] = sok;
        }
        tf0 = tf[0]; tf1 = tf[1]; tf2 = tf[2];
        skm0 = sk[0]; skm1 = sk[1]; skm2 = sk[2];
    }
    const float vP = (float)(lane & 1);   // parity of states 0,2
    const float vQ = 1.0f - vP;           // parity of state 1

    // ---- stage rows into LDS: slp[t] = {p1-p0, p0-pb, pb, 0}, 640 rows ----
    __shared__ f32x4 slp[640];            // zero-padded past T for deep prefetch
    {
        const float* lg = logits + (size_t)b * C;
        const size_t strideT = (size_t)B * C;
        float c0 = 0.f, c1 = 0.f, c2 = 0.f;
        if (lane < T) {
            const float* r = lg + (size_t)lane * strideT;
            c0 = r[f]; c1 = r[Ff + f]; c2 = r[2 * Ff];
        }
        #pragma unroll 1
        for (int j = 0; j < 10; ++j) {    // 10*64 = 640
            int i = lane + (j << 6);
            int inx = i + 64;
            float n0 = 0.f, n1 = 0.f, n2 = 0.f;
            if (inx < T) {                 // software-pipelined next-row loads
                const float* r = lg + (size_t)inx * strideT;
                n0 = r[f]; n1 = r[Ff + f]; n2 = r[2 * Ff];
            }
            f32x4 v = {0.f, 0.f, 0.f, 0.f};
            if (i < T) {
                float m = fmaxf(fmaxf(c0, c1), c2);
                float ep = __expf(c0 - m);
                float en = __expf(c1 - m);
                float eb = __expf(c2 - m);
                float inv = __builtin_amdgcn_rcpf(ep + en + eb);
                float p0 = ep * inv, p1 = en * inv, pb = eb * inv;
                v[0] = p1 - p0; v[1] = p0 - pb; v[2] = pb;
            }
            slp[i] = v;
            c0 = n0; c1 = n1; c2 = n2;
        }
    }
    __syncthreads();

    // ---- t = 0 init ----
    FwdState fs;
    {
        f32x4 E0 = slp[0];
        float p00 = E0[1] + E0[2];                   // p_pos row 0
        fs.a0 = (lane == 0) ? E0[2] : 0.f;           // state 0 = blank
        fs.a1 = (lane == 0 && tl > 0) ? fmaf(tf1, E0[0], p00) : 0.f;
        fs.a2 = 0.f;
        fs.s1 = 1.f; fs.k0 = skm0; fs.k1 = skm1;
        fs.esum = 0;
    }

    const int t_end = (il < T) ? il : T;

#define EMSTEP(E) { \
    float iA = fmaf(vP, E[1], E[2]); \
    float iB = fmaf(vQ, E[1], E[2]); \
    float e0 = fmaf(tf0, E[0], iA); \
    float e1 = fmaf(tf1, E[0], iB); \
    float e2 = fmaf(tf2, E[0], iA); \
    fwd_step(e0, e1, e2, fs, skm2); }

#define LOADA(tb) { FA0 = slp[(tb)];     FA1 = slp[(tb) + 1]; \
                    FA2 = slp[(tb) + 2]; FA3 = slp[(tb) + 3]; \
                    FA4 = slp[(tb) + 4]; FA5 = slp[(tb) + 5]; \
                    FA6 = slp[(tb) + 6]; FA7 = slp[(tb) + 7]; }
#define LOADB(tb) { FB0 = slp[(tb)];     FB1 = slp[(tb) + 1]; \
                    FB2 = slp[(tb) + 2]; FB3 = slp[(tb) + 3]; \
                    FB4 = slp[(tb) + 4]; FB5 = slp[(tb) + 5]; \
                    FB6 = slp[(tb) + 6]; FB7 = slp[(tb) + 7]; }
#define ANCHA asm volatile("" : "+v"(FA0), "+v"(FA1), "+v"(FA2), "+v"(FA3), \
                                "+v"(FA4), "+v"(FA5), "+v"(FA6), "+v"(FA7));
#define ANCHB asm volatile("" : "+v"(FB0), "+v"(FB1), "+v"(FB2), "+v"(FB3), \
                                "+v"(FB4), "+v"(FB5), "+v"(FB6), "+v"(FB7));

    f32x4 FA0, FA1, FA2, FA3, FA4, FA5, FA6, FA7;
    f32x4 FB0, FB1, FB2, FB3, FB4, FB5, FB6, FB7;

    LOADA(1)                         // rows 1..8
    int t = 1;
    #pragma unroll 1
    for (; t + 16 <= t_end; t += 16) {
        LOADB(t + 8)                 // rows t+8..t+15 in flight under bank A
        ANCHA                        // one compiler wait: bank A ready
        fwd_rescale(fs, skm0, skm1);
        EMSTEP(FA0) EMSTEP(FA1) EMSTEP(FA2) EMSTEP(FA3)
        EMSTEP(FA4) EMSTEP(FA5) EMSTEP(FA6) EMSTEP(FA7)
        LOADA(t + 16)                // rows t+16..t+23 in flight under bank B
        ANCHB                        // bank B ready
        fwd_rescale(fs, skm0, skm1);
        EMSTEP(FB0) EMSTEP(FB1) EMSTEP(FB2) EMSTEP(FB3)
        EMSTEP(FB4) EMSTEP(FB5) EMSTEP(FB6) EMSTEP(FB7)
    }
    // tail (<= 15 steps, growth bounded, no rescale needed)
    #pragma unroll 1
    for (; t < t_end; ++t) {
        f32x4 E = slp[t];
        EMSTEP(E)
    }
#undef EMSTEP
#undef LOADA
#undef LOADB
#undef ANCHA
#undef ANCHB

    // ---- epilogue: loss from alpha[2tl], alpha[2tl-1] with per-lane exponents ----
    __shared__ float sa[192];
    __shared__ int   se[64];
    {
        int l = 3 * lane;
        sa[l] = fs.a0; sa[l + 1] = fs.a1; sa[l + 2] = fs.a2;
        se[lane] = fs.esum;
    }
    __syncthreads();
    if (lane == 0) {
        int l1 = 2 * tl;
        int l2 = (tl > 0) ? (2 * tl - 1) : 0;
        float v1 = sa[l1];
        float v2 = (tl > 0) ? sa[l2] : 0.f;
        int e1 = se[l1 / 3];
        int e2 = (tl > 0) ? se[l2 / 3] : 0;
        int em_ = (e1 > e2) ? e1 : e2;
        float sum = ldexpf(v1, e1 - em_) + ldexpf(v2, e2 - em_);
        float ll = (__log2f(sum) + (float)em_) * LN2;
        float loss = (ll > -1e29f) ? -ll : 0.0f;
        float denom = (tl > 0) ? (float)tl : 1.0f;
        loss_out[p] = loss / denom;
    }
}

// Deterministic single-block reduction: out[0] = sum(v) / B
__global__ __launch_bounds__(256) void reduce_kernel(
    const float* __restrict__ v, float* __restrict__ out, int n, float invB)
{
    __shared__ float buf[256];
    float s = 0.f;
    for (int i = (int)threadIdx.x; i < n; i += 256) s += v[i];
    buf[threadIdx.x] = s;
    __syncthreads();
    for (int off = 128; off > 0; off >>= 1) {
        if ((int)threadIdx.x < off) buf[threadIdx.x] += buf[threadIdx.x + off];
        __syncthreads();
    }
    if (threadIdx.x == 0) out[0] = buf[0] * invB;
}

extern "C" void kernel_launch(void* const* d_in, const int* in_sizes, int n_in,
                              void* d_out, int out_size, void* d_ws, size_t ws_size,
                              hipStream_t stream) {
    const float* logits         = (const float*)d_in[0];
    const int*   targets        = (const int*)d_in[1];
    const int*   input_lengths  = (const int*)d_in[2];
    const int*   target_lengths = (const int*)d_in[3];
    float* out = (float*)d_out;

    const int B  = in_sizes[2];            // 32
    const int BF = in_sizes[3];            // B*F = 1120
    const int Ff = BF / B;                 // 35
    const int S  = in_sizes[1] / BF;       // 80
    const int C  = 2 * Ff + 1;             // 71
    const int T  = in_sizes[0] / (B * C);  // 600

    float* losses = (float*)d_ws;          // BF floats of scratch

    ctc_kernel<<<BF, 64, 0, stream>>>(logits, targets, input_lengths,
                                      target_lengths, losses, T, B, Ff, S);
    reduce_kernel<<<1, 256, 0, stream>>>(losses, out, BF, 1.0f / (float)B);
}

// Round 12
// 53.009 us; speedup vs baseline: 1.4819x; 1.1955x over previous
//
#include <hip/hip_runtime.h>

#define LN2 0.6931471805599453f

typedef float f32x4 __attribute__((ext_vector_type(4)));

// lane i <- lane i-1 (value), lane 0 <- 0.0f   (wave_shr:1)
__device__ __forceinline__ float dpp_shr1_zero(float x) {
    return __int_as_float(__builtin_amdgcn_update_dpp(
        0, __float_as_int(x), 0x138, 0xF, 0xF, true));
}
// lane i <- lane i-1 (int), lane 0 keeps own
__device__ __forceinline__ int dpp_shr1_keep(int x) {
    return __builtin_amdgcn_update_dpp(x, x, 0x138, 0xF, 0xF, false);
}
// lane i <- lane i+1 (value), lane 63 <- 0.0f  (wave_shl:1)
__device__ __forceinline__ float dpp_shl1_zero(float x) {
    return __int_as_float(__builtin_amdgcn_update_dpp(
        0, __float_as_int(x), 0x130, 0xF, 0xF, true));
}
// lane i <- lane i+1 (int), lane 63 keeps own
__device__ __forceinline__ int dpp_shl1_keep(int x) {
    return __builtin_amdgcn_update_dpp(x, x, 0x130, 0xF, 0xF, false);
}
// exact 2^clamp(d, -126, 127)
__device__ __forceinline__ float exp2i_clamped(int d) {
    int k = 127 + d;
    k = (k < 1) ? 1 : ((k > 254) ? 254 : k);
    return __uint_as_float(((unsigned)k) << 23);
}
__device__ __forceinline__ float sel3(int e, float v0, float v1, float v2) {
    return (e == 2) ? v2 : ((e == 1) ? v1 : v0);
}

struct FwdState {
    float a0, a1, a2;   // alpha (linear, scaled by 2^-esum)
    float s1, k0, k1;   // 2^(eL-e), skm0*s1, skm1*s1
    int   esum;
};
struct BwdState {
    float c0, c1, c2;   // gamma = emit*beta (linear, scaled by 2^-esum)
    float s1b, kA, kB;  // 2^(eR-e), sknA*s1b, sknB*s1b
    int   esum;
};

// 11 VALU per step (proven exact R4-R6)
__device__ __forceinline__ void fwd_step(float em0, float em1, float em2,
                                         FwdState& st, float skm2) {
    float d2 = dpp_shr1_zero(st.a2);
    float d1 = dpp_shr1_zero(st.a1);
    float n0 = fmaf(st.k0, d1, fmaf(st.s1, d2, st.a0)) * em0;
    float n1 = fmaf(st.k1, d2, st.a1 + st.a0) * em1;
    float n2 = fmaf(skm2, st.a0, st.a2 + st.a1) * em2;
    st.a0 = n0; st.a1 = n1; st.a2 = n2;
}
// mirror (proven exact R8)
__device__ __forceinline__ void bwd_step(float em0, float em1, float em2,
                                         BwdState& st, float skm2) {
    float d3 = dpp_shl1_zero(st.c0);
    float d4 = dpp_shl1_zero(st.c1);
    float n0 = fmaf(skm2, st.c2, st.c0 + st.c1) * em0;
    float n1 = fmaf(st.kA, d3, st.c1 + st.c2) * em1;
    float n2 = fmaf(st.kB, d4, fmaf(st.s1b, d3, st.c2)) * em2;
    st.c0 = n0; st.c1 = n1; st.c2 = n2;
}

// Every 8 steps (proven exact R6)
__device__ __forceinline__ void fwd_rescale(FwdState& st, float skm0, float skm1) {
    float m = fmaxf(fmaxf(st.a0, st.a1), st.a2);
    int ebits = (int)(__float_as_uint(m) >> 23);
    bool dead = (ebits == 0);
    int de = dead ? 0 : (127 - ebits);
    float scz = dead ? 0.0f : exp2i_clamped(de);
    st.a0 *= scz; st.a1 *= scz; st.a2 *= scz;
    st.esum -= de;
    #pragma unroll
    for (int r = 0; r < 5; ++r) {
        int en = dpp_shr1_keep(st.esum);
        st.esum = dead ? en : st.esum;
    }
    int enf = dpp_shr1_keep(st.esum);
    int gap = enf - st.esum;
    int adj = (gap > 64) ? (gap - 64) : 0;
    float sc3 = exp2i_clamped(-adj);
    st.a0 *= sc3; st.a1 *= sc3; st.a2 *= sc3;
    st.esum += adj;
    st.s1 = exp2i_clamped(gap - adj);
    st.k0 = skm0 * st.s1;
    st.k1 = skm1 * st.s1;
}
// R8-hardened bwd rescale (proven exact R8)
__device__ __forceinline__ void bwd_rescale(BwdState& st, float sknA, float sknB) {
    float m = fmaxf(fmaxf(st.c0, st.c1), st.c2);
    int ebits = (int)(__float_as_uint(m) >> 23);
    bool dead = (ebits == 0);
    int de = dead ? 0 : (127 - ebits);
    float scz = dead ? 0.0f : exp2i_clamped(de);
    st.c0 *= scz; st.c1 *= scz; st.c2 *= scz;
    st.esum -= de;
    #pragma unroll
    for (int r = 0; r < 5; ++r) {
        int en = dpp_shl1_keep(st.esum);
        st.esum = dead ? en : st.esum;
    }
    #pragma unroll
    for (int r = 0; r < 3; ++r) {
        int enl = dpp_shr1_keep(st.esum);
        int mn = (enl < st.esum) ? enl : st.esum;
        st.esum = dead ? mn : st.esum;
    }
    int deadR = dpp_shl1_keep(dead ? 1 : 0);
    int enf = dpp_shl1_keep(st.esum);
    int gap = enf - st.esum;
    int adj = (gap > 64) ? (gap - 64) : 0;
    adj = (adj > 126) ? 126 : adj;
    adj = deadR ? 0 : adj;
    float sc3 = exp2i_clamped(-adj);
    st.c0 *= sc3; st.c1 *= sc3; st.c2 *= sc3;
    st.esum += adj;
    float s1b = exp2i_clamped(gap - adj);
    st.s1b = deadR ? 0.f : s1b;
    st.kA = sknA * st.s1b;
    st.kB = sknB * st.s1b;
}

// Two waves per (b,f): wave 0 = alpha forward rows 1..m (R6 loop), wave 1 =
// gamma backward rows TL-2..m+1 (R8 loop). Serial depth halved per wave; the
// waves run concurrently on different SIMDs. Midpoint combine = R8 epilogue.
__global__ __launch_bounds__(128, 1) void ctc_kernel(
    const float* __restrict__ logits,        // [T, B, 2F+1]
    const int* __restrict__ targets,         // [B, F, S]
    const int* __restrict__ input_lengths,   // [B]
    const int* __restrict__ target_lengths,  // [B, F]
    float* __restrict__ loss_out,            // [B*F] (loss / tl)
    int T, int B, int Ff, int S)
{
    const int p = blockIdx.x;
    const int b = p / Ff;
    const int f = p - b * Ff;
    const int tid = (int)threadIdx.x;
    const int wid = tid >> 6;
    const int lane = tid & 63;
    const int C = 2 * Ff + 1;
    const int L = 2 * S + 1;

    const int tl = target_lengths[p];
    const int il = input_lengths[b];
    const int tbase = p * S;

    // ---- per-lane static metadata: states l = 3*lane + j ----
    int e0i, e1i, e2i;
    float skm0, skm1, skm2;
    {
        int e[3]; float sk[3];
        const int l0 = 3 * lane;
        #pragma unroll
        for (int j = 0; j < 3; ++j) {
            int l = l0 + j;
            int ev = 2; float sok = 0.f;
            if (l < L && (l & 1)) {
                int s = (l - 1) >> 1;
                ev = targets[tbase + s];
                if (s >= 1) sok = (targets[tbase + s - 1] != ev) ? 1.f : 0.f;
            }
            e[j] = ev; sk[j] = sok;
        }
        e0i = e[0]; e1i = e[1]; e2i = e[2];
        skm0 = sk[0]; skm1 = sk[1]; skm2 = sk[2];
    }
    const float sknA = dpp_shl1_zero(skm0);   // skip_ok(l0+3)
    const float sknB = dpp_shl1_zero(skm1);   // skip_ok(l0+4)

    // ---- stage linear softmax into LDS (128 threads, software-pipelined) ----
    __shared__ f32x4 slp[640];                // {p_pos, p_neg, p_blank, 0}, zero-padded
    {
        const float* lg = logits + (size_t)b * C;
        const size_t strideT = (size_t)B * C;
        float c0 = 0.f, c1 = 0.f, c2 = 0.f;
        if (tid < T) {
            const float* r = lg + (size_t)tid * strideT;
            c0 = r[f]; c1 = r[Ff + f]; c2 = r[2 * Ff];
        }
        #pragma unroll 1
        for (int j = 0; j < 5; ++j) {         // 5*128 = 640
            int i = tid + (j << 7);
            int inx = i + 128;
            float n0 = 0.f, n1 = 0.f, n2 = 0.f;
            if (inx < T) {
                const float* r = lg + (size_t)inx * strideT;
                n0 = r[f]; n1 = r[Ff + f]; n2 = r[2 * Ff];
            }
            f32x4 v = {0.f, 0.f, 0.f, 0.f};
            if (i < T) {
                float m = fmaxf(fmaxf(c0, c1), c2);
                float ep = __expf(c0 - m);
                float en = __expf(c1 - m);
                float eb = __expf(c2 - m);
                float inv = __builtin_amdgcn_rcpf(ep + en + eb);
                v[0] = ep * inv; v[1] = en * inv; v[2] = eb * inv;
            }
            if (i < 640) slp[i] = v;
            c0 = n0; c1 = n1; c2 = n2;
        }
    }
    __syncthreads();

    // per-lane emission base pointers (byte offset e*4 within each 16B row)
    const char* base8 = (const char*)slp;
    const char* qt0 = base8 + (e0i << 2);
    const char* qt1 = base8 + (e1i << 2);
    const char* qt2 = base8 + (e2i << 2);

    const int TL = (il < T) ? il : T;
    const int m_ = (TL >= 2) ? ((TL - 1) >> 1) : 0;
    const int Fn = m_;                               // fwd steps: rows 1..m_
    const int Bk = (TL >= 2) ? (TL - 2 - m_) : 0;    // bwd steps: rows TL-2..m_+1

    // ---- epilogue shared buffers ----
    __shared__ float sa[192];
    __shared__ float sg[194];
    __shared__ int   seb[65];
    __shared__ float sdot[64];
    __shared__ int   sE[64];

    FwdState fs;
    fs.a0 = 0.f; fs.a1 = 0.f; fs.a2 = 0.f; fs.s1 = 1.f;
    fs.k0 = skm0; fs.k1 = skm1; fs.esum = 0;

    if (wid == 0) {
        // ================= FORWARD WAVE (R6 loop, verbatim) =================
        {
            f32x4 E0 = slp[0];
            fs.a0 = (lane == 0) ? E0[2] : 0.f;
            fs.a1 = (lane == 0 && tl > 0) ? sel3(e1i, E0[0], E0[1], E0[2]) : 0.f;
            fs.a2 = 0.f;
        }
        const int t_endF = Fn + 1;                   // process t = 1..Fn
        const char* pr0 = qt0 + 16;
        const char* pr1 = qt1 + 16;
        const char* pr2 = qt2 + 16;
#define LDE(OFF, E) { E[0] = *(const float*)(pr0 + (OFF)); \
                      E[1] = *(const float*)(pr1 + (OFF)); \
                      E[2] = *(const float*)(pr2 + (OFF)); }
        float A0[3], A1[3], A2[3], A3[3], B0[3], B1[3], B2[3], B3[3];
        float C0[3], C1[3], C2[3], C3[3], D0[3], D1[3], D2[3], D3[3];
        int t = 1;
        if (t + 15 < t_endF) {
            LDE(  0, A0); LDE( 16, A1); LDE( 32, A2); LDE( 48, A3);
            LDE( 64, B0); LDE( 80, B1); LDE( 96, B2); LDE(112, B3);
            LDE(128, C0); LDE(144, C1); LDE(160, C2); LDE(176, C3);
            LDE(192, D0); LDE(208, D1); LDE(224, D2); LDE(240, D3);
        }
        #pragma unroll 1
        for (; t + 15 < t_endF; t += 16) {
            fwd_rescale(fs, skm0, skm1);
            fwd_step(A0[0], A0[1], A0[2], fs, skm2);
            fwd_step(A1[0], A1[1], A1[2], fs, skm2);
            fwd_step(A2[0], A2[1], A2[2], fs, skm2);
            fwd_step(A3[0], A3[1], A3[2], fs, skm2);
            LDE(256, A0); LDE(272, A1); LDE(288, A2); LDE(304, A3);
            fwd_step(B0[0], B0[1], B0[2], fs, skm2);
            fwd_step(B1[0], B1[1], B1[2], fs, skm2);
            fwd_step(B2[0], B2[1], B2[2], fs, skm2);
            fwd_step(B3[0], B3[1], B3[2], fs, skm2);
            LDE(320, B0); LDE(336, B1); LDE(352, B2); LDE(368, B3);
            fwd_rescale(fs, skm0, skm1);
            fwd_step(C0[0], C0[1], C0[2], fs, skm2);
            fwd_step(C1[0], C1[1], C1[2], fs, skm2);
            fwd_step(C2[0], C2[1], C2[2], fs, skm2);
            fwd_step(C3[0], C3[1], C3[2], fs, skm2);
            LDE(384, C0); LDE(400, C1); LDE(416, C2); LDE(432, C3);
            fwd_step(D0[0], D0[1], D0[2], fs, skm2);
            fwd_step(D1[0], D1[1], D1[2], fs, skm2);
            fwd_step(D2[0], D2[1], D2[2], fs, skm2);
            fwd_step(D3[0], D3[1], D3[2], fs, skm2);
            LDE(448, D0); LDE(464, D1); LDE(480, D2); LDE(496, D3);
            pr0 += 256; pr1 += 256; pr2 += 256;
        }
#undef LDE
        #pragma unroll 1
        for (; t < t_endF; ++t) {
            int o = t << 4;
            float e0 = *(const float*)(qt0 + o);
            float e1 = *(const float*)(qt1 + o);
            float e2 = *(const float*)(qt2 + o);
            fwd_step(e0, e1, e2, fs, skm2);
        }
        {
            int l = 3 * lane;
            sa[l] = fs.a0; sa[l + 1] = fs.a1; sa[l + 2] = fs.a2;
        }
    } else {
        // ================= BACKWARD WAVE (R8 loop) =================
        BwdState bs;
        {
            int oTL = (TL - 1) << 4;
            float eL0 = *(const float*)(qt0 + oTL);
            float eL1 = *(const float*)(qt1 + oTL);
            float eL2 = *(const float*)(qt2 + oTL);
            int l0i = 3 * lane;
            int end1 = 2 * tl, end2 = 2 * tl - 1;
            bs.c0 = (l0i == end1 || l0i == end2) ? eL0 : 0.f;
            bs.c1 = (l0i + 1 == end1 || l0i + 1 == end2) ? eL1 : 0.f;
            bs.c2 = (l0i + 2 == end1 || l0i + 2 == end2) ? eL2 : 0.f;
            bs.s1b = 1.f; bs.kA = sknA; bs.kB = sknB;
            bs.esum = 0;
        }
        const char* pb0 = qt0 + ((TL - 2) << 4);
        const char* pb1 = qt1 + ((TL - 2) << 4);
        const char* pb2 = qt2 + ((TL - 2) << 4);
#define LDB(OFF, E) { E[0] = *(const float*)(pb0 - (OFF)); \
                      E[1] = *(const float*)(pb1 - (OFF)); \
                      E[2] = *(const float*)(pb2 - (OFF)); }
        float GA0[3], GA1[3], GA2[3], GA3[3], GB0[3], GB1[3], GB2[3], GB3[3];
        float GC0[3], GC1[3], GC2[3], GC3[3], GD0[3], GD1[3], GD2[3], GD3[3];
        int k = 0;
        if (k + 15 < Bk) {
            LDB(  0, GA0); LDB( 16, GA1); LDB( 32, GA2); LDB( 48, GA3);
            LDB( 64, GB0); LDB( 80, GB1); LDB( 96, GB2); LDB(112, GB3);
            LDB(128, GC0); LDB(144, GC1); LDB(160, GC2); LDB(176, GC3);
            LDB(192, GD0); LDB(208, GD1); LDB(224, GD2); LDB(240, GD3);
        }
        #pragma unroll 1
        for (; k + 15 < Bk; k += 16) {
            bwd_rescale(bs, sknA, sknB);
            bwd_step(GA0[0], GA0[1], GA0[2], bs, skm2);
            bwd_step(GA1[0], GA1[1], GA1[2], bs, skm2);
            bwd_step(GA2[0], GA2[1], GA2[2], bs, skm2);
            bwd_step(GA3[0], GA3[1], GA3[2], bs, skm2);
            LDB(256, GA0); LDB(272, GA1); LDB(288, GA2); LDB(304, GA3);
            bwd_step(GB0[0], GB0[1], GB0[2], bs, skm2);
            bwd_step(GB1[0], GB1[1], GB1[2], bs, skm2);
            bwd_step(GB2[0], GB2[1], GB2[2], bs, skm2);
            bwd_step(GB3[0], GB3[1], GB3[2], bs, skm2);
            LDB(320, GB0); LDB(336, GB1); LDB(352, GB2); LDB(368, GB3);
            bwd_rescale(bs, sknA, sknB);
            bwd_step(GC0[0], GC0[1], GC0[2], bs, skm2);
            bwd_step(GC1[0], GC1[1], GC1[2], bs, skm2);
            bwd_step(GC2[0], GC2[1], GC2[2], bs, skm2);
            bwd_step(GC3[0], GC3[1], GC3[2], bs, skm2);
            LDB(384, GC0); LDB(400, GC1); LDB(416, GC2); LDB(432, GC3);
            bwd_step(GD0[0], GD0[1], GD0[2], bs, skm2);
            bwd_step(GD1[0], GD1[1], GD1[2], bs, skm2);
            bwd_step(GD2[0], GD2[1], GD2[2], bs, skm2);
            bwd_step(GD3[0], GD3[1], GD3[2], bs, skm2);
            LDB(448, GD0); LDB(464, GD1); LDB(480, GD2); LDB(496, GD3);
            pb0 -= 256; pb1 -= 256; pb2 -= 256;
        }
#undef LDB
        int trow = TL - 2 - k;
        #pragma unroll 1
        for (; trow >= m_ + 1; --trow) {
            int o = trow << 4;
            float g0 = *(const float*)(qt0 + o);
            float g1 = *(const float*)(qt1 + o);
            float g2 = *(const float*)(qt2 + o);
            bwd_step(g0, g1, g2, bs, skm2);
        }
        {
            int l = 3 * lane;
            sg[l] = bs.c0; sg[l + 1] = bs.c1; sg[l + 2] = bs.c2;
            seb[lane] = bs.esum;
            if (lane == 0) { sg[192] = 0.f; sg[193] = 0.f; seb[64] = 0; }
        }
    }
    __syncthreads();

    // ---- midpoint combine (R8 epilogue, fs in wave-0 regs, bwd via LDS) ----
    if (wid == 0) {
        int eB = seb[lane];
        float scn = exp2i_clamped(seb[lane + 1] - eB);
        float g0 = sg[3 * lane], g1 = sg[3 * lane + 1], g2 = sg[3 * lane + 2];
        float g3 = sg[3 * lane + 3] * scn;
        float g4 = sg[3 * lane + 4] * scn;
        float s0 = fmaf(skm2, g2, g0 + g1);
        float s1 = fmaf(sknA, g3, g1 + g2);
        float s2 = fmaf(sknB, g4, g2 + g3);
        float dot = fs.a0 * s0 + fs.a1 * s1 + fs.a2 * s2;
        sdot[lane] = dot;
        sE[lane] = fs.esum + eB;
    }
    __syncthreads();
    if (tid == 0) {
        float loss = 0.f;
        if (TL == 1) {
            float v = sa[2 * tl] + ((tl > 0) ? sa[2 * tl - 1] : 0.f);
            if (v > 0.f) loss = -(__log2f(v) * LN2);
        } else {
            int Emax = -0x40000000;
            for (int i = 0; i < 64; ++i)
                if (sdot[i] > 0.f && sE[i] > Emax) Emax = sE[i];
            if (Emax != -0x40000000) {
                float sum = 0.f;
                for (int i = 0; i < 64; ++i) {
                    int d = sE[i] - Emax;
                    if (d > -127 && sdot[i] > 0.f) sum += sdot[i] * exp2i_clamped(d);
                }
                loss = -((__log2f(sum) + (float)Emax) * LN2);
            }
        }
        float denom = (tl > 0) ? (float)tl : 1.0f;
        loss_out[p] = loss / denom;
    }
}

// Deterministic single-block reduction: out[0] = sum(v) / B
__global__ __launch_bounds__(256) void reduce_kernel(
    const float* __restrict__ v, float* __restrict__ out, int n, float invB)
{
    __shared__ float buf[256];
    float s = 0.f;
    for (int i = (int)threadIdx.x; i < n; i += 256) s += v[i];
    buf[threadIdx.x] = s;
    __syncthreads();
    for (int off = 128; off > 0; off >>= 1) {
        if ((int)threadIdx.x < off) buf[threadIdx.x] += buf[threadIdx.x + off];
        __syncthreads();
    }
    if (threadIdx.x == 0) out[0] = buf[0] * invB;
}

extern "C" void kernel_launch(void* const* d_in, const int* in_sizes, int n_in,
                              void* d_out, int out_size, void* d_ws, size_t ws_size,
                              hipStream_t stream) {
    const float* logits         = (const float*)d_in[0];
    const int*   targets        = (const int*)d_in[1];
    const int*   input_lengths  = (const int*)d_in[2];
    const int*   target_lengths = (const int*)d_in[3];
    float* out = (float*)d_out;

    const int B  = in_sizes[2];            // 32
    const int BF = in_sizes[3];            // B*F = 1120
    const int Ff = BF / B;                 // 35
    const int S  = in_sizes[1] / BF;       // 80
    const int C  = 2 * Ff + 1;             // 71
    const int T  = in_sizes[0] / (B * C);  // 600

    float* losses = (float*)d_ws;          // BF floats of scratch

    ctc_kernel<<<BF, 128, 0, stream>>>(logits, targets, input_lengths,
                                       target_lengths, losses, T, B, Ff, S);
    reduce_kernel<<<1, 256, 0, stream>>>(losses, out, BF, 1.0f / (float)B);
}